// Round 1
// baseline (1399.411 us; speedup 1.0000x reference)
//
#include <hip/hip_runtime.h>

#define N_NODES 50000
#define N_EDGES 1600000
#define D_IN 192
#define D_HID 128

// ---------------- CSR build ----------------

__global__ void hist_kernel(const int* __restrict__ dst, int E, int* __restrict__ cnt) {
    int e = blockIdx.x * blockDim.x + threadIdx.x;
    if (e < E) atomicAdd(&cnt[dst[e]], 1);
}

__global__ __launch_bounds__(1024) void scan_kernel(const int* __restrict__ cnt,
        int* __restrict__ row_ptr, int* __restrict__ fill, float* __restrict__ dhis, int n) {
    __shared__ int partial[1024];
    int tid = threadIdx.x;
    int chunk = (n + 1023) >> 10;
    int start = tid * chunk;
    int end = min(start + chunk, n);
    int s = 0;
    for (int i = start; i < end; ++i) s += cnt[i];
    partial[tid] = s;
    __syncthreads();
    for (int off = 1; off < 1024; off <<= 1) {
        int add = (tid >= off) ? partial[tid - off] : 0;
        __syncthreads();
        partial[tid] += add;
        __syncthreads();
    }
    int prefix = (tid > 0) ? partial[tid - 1] : 0;
    for (int i = start; i < end; ++i) {
        int c = cnt[i];
        row_ptr[i] = prefix;
        fill[i] = prefix;
        dhis[i] = rsqrtf((float)c + 1.0f);
        prefix += c;
    }
    if (tid == 0) row_ptr[n] = partial[1023];
}

__global__ void fill_kernel(const int* __restrict__ src, const int* __restrict__ dst, int E,
                            int* __restrict__ fill, int* __restrict__ esrc) {
    int e = blockIdx.x * blockDim.x + threadIdx.x;
    if (e < E) {
        int slot = atomicAdd(&fill[dst[e]], 1);
        esrc[slot] = src[e];
    }
}

// ---------------- GEMM: C[M,128] = A[M,K](lda) @ W[K,128] + bias ----------------
// Tile: BM=64, BN=128(full), BK=16; 256 threads; 4x8 micro-tile per thread.

__global__ __launch_bounds__(256) void gemm_kernel(const float* __restrict__ A, int lda,
        const float* __restrict__ W, const float* __restrict__ bias,
        float* __restrict__ C, int M, int K) {
    __shared__ float As[16][64];   // transposed: As[k][row]
    __shared__ float Bs[16][128];

    int tid = threadIdx.x;
    int tx = tid & 15;      // col group: cols tx*8 .. tx*8+7
    int ty = tid >> 4;      // row group: rows ty*4 .. ty*4+3
    int row0 = blockIdx.x * 64;

    float acc[4][8];
#pragma unroll
    for (int i = 0; i < 4; ++i)
#pragma unroll
        for (int j = 0; j < 8; ++j) acc[i][j] = 0.0f;

    int arow = tid >> 2;          // 0..63
    int akk  = (tid & 3) * 4;     // 0,4,8,12
    int brow = tid >> 5;          // 0..7
    int bcol = (tid & 31) * 4;    // 0..124

    for (int k0 = 0; k0 < K; k0 += 16) {
        // Stage A tile (64 x 16), transposed into LDS
        {
            int grow = row0 + arow;
            int crow = grow < M ? grow : (M - 1);
            const float* ap = A + (size_t)crow * lda + k0 + akk;
            float4 v = *(const float4*)ap;
            if (grow >= M) { v.x = 0.f; v.y = 0.f; v.z = 0.f; v.w = 0.f; }
            As[akk + 0][arow] = v.x;
            As[akk + 1][arow] = v.y;
            As[akk + 2][arow] = v.z;
            As[akk + 3][arow] = v.w;
        }
        // Stage B tile (16 x 128)
        {
            const float* wp = W + (size_t)(k0 + brow) * 128 + bcol;
            *(float4*)&Bs[brow][bcol] = *(const float4*)wp;
            const float* wp2 = W + (size_t)(k0 + brow + 8) * 128 + bcol;
            *(float4*)&Bs[brow + 8][bcol] = *(const float4*)wp2;
        }
        __syncthreads();
#pragma unroll
        for (int k = 0; k < 16; ++k) {
            float4 a  = *(const float4*)&As[k][ty * 4];
            float4 b0 = *(const float4*)&Bs[k][tx * 8];
            float4 b1 = *(const float4*)&Bs[k][tx * 8 + 4];
            float av[4] = {a.x, a.y, a.z, a.w};
            float bv[8] = {b0.x, b0.y, b0.z, b0.w, b1.x, b1.y, b1.z, b1.w};
#pragma unroll
            for (int i = 0; i < 4; ++i)
#pragma unroll
                for (int j = 0; j < 8; ++j)
                    acc[i][j] = fmaf(av[i], bv[j], acc[i][j]);
        }
        __syncthreads();
    }

    float bias8[8];
#pragma unroll
    for (int j = 0; j < 8; ++j) bias8[j] = bias[tx * 8 + j];

#pragma unroll
    for (int i = 0; i < 4; ++i) {
        int r = row0 + ty * 4 + i;
        if (r < M) {
            float4 o0, o1;
            o0.x = acc[i][0] + bias8[0]; o0.y = acc[i][1] + bias8[1];
            o0.z = acc[i][2] + bias8[2]; o0.w = acc[i][3] + bias8[3];
            o1.x = acc[i][4] + bias8[4]; o1.y = acc[i][5] + bias8[5];
            o1.z = acc[i][6] + bias8[6]; o1.w = acc[i][7] + bias8[7];
            float* cp = C + (size_t)r * 128 + tx * 8;
            *(float4*)cp = o0;
            *(float4*)(cp + 4) = o1;
        }
    }
}

// ---------------- Fused dual-view aggregation + combine + relu ----------------
// Per dst node (one block of 128 threads, one feature per thread):
//   a1 = sum_e h1[src], g1 = sum_e h1[src]*dhis[src]  (same for h2)
//   o1 = relu(dhis[d]*g1 + h1[d]*dhis[d]^2 + a2*D_inv[d])
//   o2 = relu(dhis[d]*g2 + h2[d]*dhis[d]^2 + a1*D_inv[d])

__global__ __launch_bounds__(128) void agg_kernel(
        const float* __restrict__ h1, const float* __restrict__ h2,
        const int* __restrict__ row_ptr, const int* __restrict__ esrc,
        const float* __restrict__ dhis, const float* __restrict__ D_inv,
        float* __restrict__ out_q, float* __restrict__ out_p, int n) {
    int d = blockIdx.x;
    int f = threadIdx.x;
    int e0 = row_ptr[d], e1 = row_ptr[d + 1];

    float a1 = 0.f, g1 = 0.f, a2 = 0.f, g2 = 0.f;
    for (int e = e0; e < e1; ++e) {
        int s = esrc[e];
        float ds = dhis[s];
        float v1 = h1[(size_t)s * 128 + f];
        float v2 = h2[(size_t)s * 128 + f];
        a1 += v1;
        g1 = fmaf(v1, ds, g1);
        a2 += v2;
        g2 = fmaf(v2, ds, g2);
    }
    float dh = dhis[d];
    float di = D_inv[d];
    float hs1 = h1[(size_t)d * 128 + f];
    float hs2 = h2[(size_t)d * 128 + f];
    float o1 = fmaf(dh, g1, fmaf(hs1, dh * dh, a2 * di));
    float o2 = fmaf(dh, g2, fmaf(hs2, dh * dh, a1 * di));
    out_q[(size_t)d * 384 + f] = fmaxf(o1, 0.f);
    out_p[(size_t)d * 384 + f] = fmaxf(o2, 0.f);
}

// ---------------- launcher ----------------

extern "C" void kernel_launch(void* const* d_in, const int* in_sizes, int n_in,
                              void* d_out, int out_size, void* d_ws, size_t ws_size,
                              hipStream_t stream) {
    const float* x     = (const float*)d_in[0];
    const float* view2 = (const float*)d_in[1];
    const int*   eidx  = (const int*)d_in[2];
    const float* D_inv = (const float*)d_in[3];
    const float* W1 = (const float*)d_in[4];  const float* b1 = (const float*)d_in[5];
    const float* W2 = (const float*)d_in[6];  const float* b2 = (const float*)d_in[7];
    const float* W3 = (const float*)d_in[8];  const float* b3 = (const float*)d_in[9];
    const float* W4 = (const float*)d_in[10]; const float* b4 = (const float*)d_in[11];
    const float* W5 = (const float*)d_in[12]; const float* b5 = (const float*)d_in[13];
    const float* W6 = (const float*)d_in[14]; const float* b6 = (const float*)d_in[15];

    const int n = N_NODES;
    const int E = N_EDGES;
    const int* src  = eidx;
    const int* dstv = eidx + E;

    // workspace bump allocator (256B aligned)
    char* ws = (char*)d_ws;
    size_t off = 0;
    auto alloc = [&](size_t bytes) -> void* {
        void* p = ws + off;
        off += (bytes + 255) & ~(size_t)255;
        return p;
    };
    int*   cnt     = (int*)alloc((size_t)n * 4);
    int*   row_ptr = (int*)alloc((size_t)(n + 1) * 4);
    int*   fill    = (int*)alloc((size_t)n * 4);
    float* dhis    = (float*)alloc((size_t)n * 4);
    int*   esrc    = (int*)alloc((size_t)E * 4);
    float* h1      = (float*)alloc((size_t)n * 128 * 4);
    float* h2      = (float*)alloc((size_t)n * 128 * 4);

    float* qb = (float*)d_out;
    float* pb = qb + (size_t)n * 384;

    // --- CSR build ---
    hipMemsetAsync(cnt, 0, (size_t)n * 4, stream);
    int eblocks = (E + 255) / 256;
    hist_kernel<<<eblocks, 256, 0, stream>>>(dstv, E, cnt);
    scan_kernel<<<1, 1024, 0, stream>>>(cnt, row_ptr, fill, dhis, n);
    fill_kernel<<<eblocks, 256, 0, stream>>>(src, dstv, E, fill, esrc);

    int gblocks = (n + 63) / 64;

    // --- layer 1 ---
    gemm_kernel<<<gblocks, 256, 0, stream>>>(x,     D_IN, W1, b1, h1, n, D_IN);
    gemm_kernel<<<gblocks, 256, 0, stream>>>(view2, D_IN, W4, b4, h2, n, D_IN);
    agg_kernel<<<n, 128, 0, stream>>>(h1, h2, row_ptr, esrc, dhis, D_inv, qb + 0, pb + 0, n);

    // --- layer 2 (reads x1/x2 from d_out with stride 384) ---
    gemm_kernel<<<gblocks, 256, 0, stream>>>(qb, 384, W2, b2, h1, n, D_HID);
    gemm_kernel<<<gblocks, 256, 0, stream>>>(pb, 384, W5, b5, h2, n, D_HID);
    agg_kernel<<<n, 128, 0, stream>>>(h1, h2, row_ptr, esrc, dhis, D_inv, qb + 128, pb + 128, n);

    // --- layer 3 ---
    gemm_kernel<<<gblocks, 256, 0, stream>>>(qb + 128, 384, W3, b3, h1, n, D_HID);
    gemm_kernel<<<gblocks, 256, 0, stream>>>(pb + 128, 384, W6, b6, h2, n, D_HID);
    agg_kernel<<<n, 128, 0, stream>>>(h1, h2, row_ptr, esrc, dhis, D_inv, qb + 256, pb + 256, n);
}

// Round 2
// 1048.207 us; speedup vs baseline: 1.3351x; 1.3351x over previous
//
#include <hip/hip_runtime.h>

#define N_NODES 50000
#define N_EDGES 1600000
#define D_IN 192
#define D_HID 128

typedef __bf16 bf16x8 __attribute__((ext_vector_type(8)));
typedef float f32x4 __attribute__((ext_vector_type(4)));

__device__ __forceinline__ unsigned short f2b(float x) {
    unsigned u = __builtin_bit_cast(unsigned, x);
    u += 0x7FFFu + ((u >> 16) & 1u);          // round-to-nearest-even
    return (unsigned short)(u >> 16);
}
__device__ __forceinline__ float blo(unsigned u) {   // low bf16 of packed pair
    return __builtin_bit_cast(float, u << 16);
}
__device__ __forceinline__ float bhi(unsigned u) {   // high bf16
    return __builtin_bit_cast(float, u & 0xFFFF0000u);
}

// ---------------- CSR build ----------------

__global__ void hist_kernel(const int* __restrict__ dst, int E, int* __restrict__ cnt) {
    int e = blockIdx.x * blockDim.x + threadIdx.x;
    if (e < E) atomicAdd(&cnt[dst[e]], 1);
}

__global__ __launch_bounds__(1024) void scan_kernel(const int* __restrict__ cnt,
        int* __restrict__ row_ptr, int* __restrict__ fill, float* __restrict__ dhis, int n) {
    __shared__ int partial[1024];
    int tid = threadIdx.x;
    int chunk = (n + 1023) >> 10;
    int start = tid * chunk;
    int end = min(start + chunk, n);
    int s = 0;
    for (int i = start; i < end; ++i) s += cnt[i];
    partial[tid] = s;
    __syncthreads();
    for (int off = 1; off < 1024; off <<= 1) {
        int add = (tid >= off) ? partial[tid - off] : 0;
        __syncthreads();
        partial[tid] += add;
        __syncthreads();
    }
    int prefix = (tid > 0) ? partial[tid - 1] : 0;
    for (int i = start; i < end; ++i) {
        int c = cnt[i];
        row_ptr[i] = prefix;
        fill[i] = prefix;
        dhis[i] = rsqrtf((float)c + 1.0f);
        prefix += c;
    }
    if (tid == 0) row_ptr[n] = partial[1023];
}

__global__ void fill_kernel(const int* __restrict__ src, const int* __restrict__ dst, int E,
                            int* __restrict__ fill, int* __restrict__ esrc) {
    int e = blockIdx.x * blockDim.x + threadIdx.x;
    if (e < E) {
        int slot = atomicAdd(&fill[dst[e]], 1);
        esrc[slot] = src[e];
    }
}

// ---------------- weight prep: Wt[j][k] = bf16(W[k][j]) ----------------

__global__ void prep_w(const float* __restrict__ W, unsigned short* __restrict__ Wt, int K) {
    int idx = blockIdx.x * 256 + threadIdx.x;
    if (idx < 128 * K) {
        int j = idx / K, k = idx - j * K;
        Wt[idx] = f2b(W[(size_t)k * 128 + j]);
    }
}

// ---------------- MFMA GEMM: out_bf16[M,128] = bf16(A[M,K](lda) @ W[K,128] + b) --------
// Block 256 thr = 4 waves; BM=64 (16 rows/wave); full N=128 (8 col groups).
// A staged fp32->bf16 in LDS; Wt read from global (L1/L2-resident, 49 KB max).

__global__ __launch_bounds__(256) void gemm_mfma(
        const float* __restrict__ A, int lda, int K, int Kp,
        const unsigned short* __restrict__ Wt, const float* __restrict__ bias,
        unsigned short* __restrict__ out, int M) {
    __shared__ __align__(16) unsigned short As[64 * 200];   // row stride Kp (<=200)

    int tid = threadIdx.x;
    int row0 = blockIdx.x * 64;

    // ---- stage A panel (64 rows x K) as bf16 ----
    {
        int r = tid >> 2;          // 0..63
        int q = tid & 3;
        int grow = row0 + r;
        int crow = grow < M ? grow : (M - 1);
        int kq = K >> 2;           // 48 or 32
        const float* ap = A + (size_t)crow * lda + q * kq;
        unsigned short* sp = As + r * Kp + q * kq;
        for (int k = 0; k < kq; k += 4) {
            float4 v = *(const float4*)(ap + k);
            sp[k + 0] = f2b(v.x); sp[k + 1] = f2b(v.y);
            sp[k + 2] = f2b(v.z); sp[k + 3] = f2b(v.w);
        }
    }
    __syncthreads();

    int wave = tid >> 6, lane = tid & 63;
    int m = lane & 15, quad = lane >> 4;

    f32x4 acc[8];
#pragma unroll
    for (int g = 0; g < 8; ++g) acc[g] = (f32x4){0.f, 0.f, 0.f, 0.f};

    int nsteps = K >> 5;           // 6 or 4
    for (int ks = 0; ks < nsteps; ++ks) {
        int k0 = ks * 32 + quad * 8;
        bf16x8 af = *(const bf16x8*)(As + (wave * 16 + m) * Kp + k0);
#pragma unroll
        for (int g = 0; g < 8; ++g) {
            bf16x8 bfr = *(const bf16x8*)(Wt + (size_t)(g * 16 + m) * K + k0);
            acc[g] = __builtin_amdgcn_mfma_f32_16x16x32_bf16(af, bfr, acc[g], 0, 0, 0);
        }
    }

    // ---- epilogue: C/D layout col=lane&15, row=quad*4+reg ----
#pragma unroll
    for (int g = 0; g < 8; ++g) {
        int col = g * 16 + m;
        float bv = bias[col];
#pragma unroll
        for (int r = 0; r < 4; ++r) {
            int grow = row0 + wave * 16 + quad * 4 + r;
            if (grow < M) out[(size_t)grow * 128 + col] = f2b(acc[g][r] + bv);
        }
    }
}

// ---------------- fused dual-view aggregation + combine + relu ----------------
// One wave per dst node; lane l handles features 2l, 2l+1 (uint = 2 bf16).

__global__ __launch_bounds__(256) void agg_kernel(
        const unsigned short* __restrict__ h1b, const unsigned short* __restrict__ h2b,
        const int* __restrict__ row_ptr, const int* __restrict__ esrc,
        const float* __restrict__ dhis, const float* __restrict__ D_inv,
        float* __restrict__ out_q, float* __restrict__ out_p, int n) {
    int wave = threadIdx.x >> 6, lane = threadIdx.x & 63;
    int d = blockIdx.x * 4 + wave;
    if (d >= n) return;

    const unsigned* r1 = (const unsigned*)h1b;   // [n][64]
    const unsigned* r2 = (const unsigned*)h2b;

    int e0 = row_ptr[d], e1 = row_ptr[d + 1];
    float a1x = 0.f, a1y = 0.f, g1x = 0.f, g1y = 0.f;
    float a2x = 0.f, a2y = 0.f, g2x = 0.f, g2y = 0.f;

    int e = e0;
    for (; e + 4 <= e1; e += 4) {
        int s0 = esrc[e], s1 = esrc[e + 1], s2 = esrc[e + 2], s3 = esrc[e + 3];
        float d0 = dhis[s0], d1 = dhis[s1], d2 = dhis[s2], d3 = dhis[s3];
        unsigned u10 = r1[(size_t)s0 * 64 + lane], u11 = r1[(size_t)s1 * 64 + lane];
        unsigned u12 = r1[(size_t)s2 * 64 + lane], u13 = r1[(size_t)s3 * 64 + lane];
        unsigned u20 = r2[(size_t)s0 * 64 + lane], u21 = r2[(size_t)s1 * 64 + lane];
        unsigned u22 = r2[(size_t)s2 * 64 + lane], u23 = r2[(size_t)s3 * 64 + lane];
        float v;
        v = blo(u10); a1x += v; g1x = fmaf(v, d0, g1x);
        v = bhi(u10); a1y += v; g1y = fmaf(v, d0, g1y);
        v = blo(u11); a1x += v; g1x = fmaf(v, d1, g1x);
        v = bhi(u11); a1y += v; g1y = fmaf(v, d1, g1y);
        v = blo(u12); a1x += v; g1x = fmaf(v, d2, g1x);
        v = bhi(u12); a1y += v; g1y = fmaf(v, d2, g1y);
        v = blo(u13); a1x += v; g1x = fmaf(v, d3, g1x);
        v = bhi(u13); a1y += v; g1y = fmaf(v, d3, g1y);
        v = blo(u20); a2x += v; g2x = fmaf(v, d0, g2x);
        v = bhi(u20); a2y += v; g2y = fmaf(v, d0, g2y);
        v = blo(u21); a2x += v; g2x = fmaf(v, d1, g2x);
        v = bhi(u21); a2y += v; g2y = fmaf(v, d1, g2y);
        v = blo(u22); a2x += v; g2x = fmaf(v, d2, g2x);
        v = bhi(u22); a2y += v; g2y = fmaf(v, d2, g2y);
        v = blo(u23); a2x += v; g2x = fmaf(v, d3, g2x);
        v = bhi(u23); a2y += v; g2y = fmaf(v, d3, g2y);
    }
    for (; e < e1; ++e) {
        int s = esrc[e];
        float ds = dhis[s];
        unsigned u1 = r1[(size_t)s * 64 + lane];
        unsigned u2 = r2[(size_t)s * 64 + lane];
        float v;
        v = blo(u1); a1x += v; g1x = fmaf(v, ds, g1x);
        v = bhi(u1); a1y += v; g1y = fmaf(v, ds, g1y);
        v = blo(u2); a2x += v; g2x = fmaf(v, ds, g2x);
        v = bhi(u2); a2y += v; g2y = fmaf(v, ds, g2y);
    }

    float dh = dhis[d];
    float di = D_inv[d];
    float dh2 = dh * dh;
    unsigned us1 = r1[(size_t)d * 64 + lane];
    unsigned us2 = r2[(size_t)d * 64 + lane];

    float o1x = fmaf(dh, g1x, fmaf(blo(us1), dh2, a2x * di));
    float o1y = fmaf(dh, g1y, fmaf(bhi(us1), dh2, a2y * di));
    float o2x = fmaf(dh, g2x, fmaf(blo(us2), dh2, a1x * di));
    float o2y = fmaf(dh, g2y, fmaf(bhi(us2), dh2, a1y * di));

    float2 oq = make_float2(fmaxf(o1x, 0.f), fmaxf(o1y, 0.f));
    float2 op = make_float2(fmaxf(o2x, 0.f), fmaxf(o2y, 0.f));
    *(float2*)(out_q + (size_t)d * 384 + lane * 2) = oq;
    *(float2*)(out_p + (size_t)d * 384 + lane * 2) = op;
}

// ---------------- launcher ----------------

extern "C" void kernel_launch(void* const* d_in, const int* in_sizes, int n_in,
                              void* d_out, int out_size, void* d_ws, size_t ws_size,
                              hipStream_t stream) {
    const float* x     = (const float*)d_in[0];
    const float* view2 = (const float*)d_in[1];
    const int*   eidx  = (const int*)d_in[2];
    const float* D_inv = (const float*)d_in[3];
    const float* W1 = (const float*)d_in[4];  const float* b1 = (const float*)d_in[5];
    const float* W2 = (const float*)d_in[6];  const float* b2 = (const float*)d_in[7];
    const float* W3 = (const float*)d_in[8];  const float* b3 = (const float*)d_in[9];
    const float* W4 = (const float*)d_in[10]; const float* b4 = (const float*)d_in[11];
    const float* W5 = (const float*)d_in[12]; const float* b5 = (const float*)d_in[13];
    const float* W6 = (const float*)d_in[14]; const float* b6 = (const float*)d_in[15];

    const int n = N_NODES;
    const int E = N_EDGES;
    const int* src  = eidx;
    const int* dstv = eidx + E;

    char* ws = (char*)d_ws;
    size_t off = 0;
    auto alloc = [&](size_t bytes) -> void* {
        void* p = ws + off;
        off += (bytes + 255) & ~(size_t)255;
        return p;
    };
    int*   cnt     = (int*)alloc((size_t)n * 4);
    int*   row_ptr = (int*)alloc((size_t)(n + 1) * 4);
    int*   fill    = (int*)alloc((size_t)n * 4);
    float* dhis    = (float*)alloc((size_t)n * 4);
    int*   esrc    = (int*)alloc((size_t)E * 4);
    unsigned short* h1b = (unsigned short*)alloc((size_t)n * 128 * 2);
    unsigned short* h2b = (unsigned short*)alloc((size_t)n * 128 * 2);
    unsigned short* Wt1 = (unsigned short*)alloc((size_t)128 * 192 * 2);
    unsigned short* Wt4 = (unsigned short*)alloc((size_t)128 * 192 * 2);
    unsigned short* Wt2 = (unsigned short*)alloc((size_t)128 * 128 * 2);
    unsigned short* Wt3 = (unsigned short*)alloc((size_t)128 * 128 * 2);
    unsigned short* Wt5 = (unsigned short*)alloc((size_t)128 * 128 * 2);
    unsigned short* Wt6 = (unsigned short*)alloc((size_t)128 * 128 * 2);

    float* qb = (float*)d_out;
    float* pb = qb + (size_t)n * 384;

    // --- CSR build ---
    hipMemsetAsync(cnt, 0, (size_t)n * 4, stream);
    int eblocks = (E + 255) / 256;
    hist_kernel<<<eblocks, 256, 0, stream>>>(dstv, E, cnt);
    scan_kernel<<<1, 1024, 0, stream>>>(cnt, row_ptr, fill, dhis, n);
    fill_kernel<<<eblocks, 256, 0, stream>>>(src, dstv, E, fill, esrc);

    // --- weight transposes (bf16) ---
    prep_w<<<(128 * 192 + 255) / 256, 256, 0, stream>>>(W1, Wt1, 192);
    prep_w<<<(128 * 192 + 255) / 256, 256, 0, stream>>>(W4, Wt4, 192);
    prep_w<<<(128 * 128 + 255) / 256, 256, 0, stream>>>(W2, Wt2, 128);
    prep_w<<<(128 * 128 + 255) / 256, 256, 0, stream>>>(W3, Wt3, 128);
    prep_w<<<(128 * 128 + 255) / 256, 256, 0, stream>>>(W5, Wt5, 128);
    prep_w<<<(128 * 128 + 255) / 256, 256, 0, stream>>>(W6, Wt6, 128);

    int gblocks = (n + 63) / 64;
    int ablocks = (n + 3) / 4;

    // --- layer 1 ---
    gemm_mfma<<<gblocks, 256, 0, stream>>>(x,     D_IN, 192, 200, Wt1, b1, h1b, n);
    gemm_mfma<<<gblocks, 256, 0, stream>>>(view2, D_IN, 192, 200, Wt4, b4, h2b, n);
    agg_kernel<<<ablocks, 256, 0, stream>>>(h1b, h2b, row_ptr, esrc, dhis, D_inv, qb + 0, pb + 0, n);

    // --- layer 2 ---
    gemm_mfma<<<gblocks, 256, 0, stream>>>(qb, 384, 128, 136, Wt2, b2, h1b, n);
    gemm_mfma<<<gblocks, 256, 0, stream>>>(pb, 384, 128, 136, Wt5, b5, h2b, n);
    agg_kernel<<<ablocks, 256, 0, stream>>>(h1b, h2b, row_ptr, esrc, dhis, D_inv, qb + 128, pb + 128, n);

    // --- layer 3 ---
    gemm_mfma<<<gblocks, 256, 0, stream>>>(qb + 128, 384, 128, 136, Wt3, b3, h1b, n);
    gemm_mfma<<<gblocks, 256, 0, stream>>>(pb + 128, 384, 128, 136, Wt6, b6, h2b, n);
    agg_kernel<<<ablocks, 256, 0, stream>>>(h1b, h2b, row_ptr, esrc, dhis, D_inv, qb + 256, pb + 256, n);
}